// Round 13
// baseline (285.439 us; speedup 1.0000x reference)
//
#include <hip/hip_runtime.h>
#include <math.h>

#define BATCH  8
#define SEQLEN 4096
#define HID    1024
#define STATE  64
#define NC     16
#define TC     (SEQLEN / NC)   // 256 steps per chunk
#define TT     32              // time rows per LDS tile (k1/scalar path)
#define NTILE  (TC / TT)
#define DBLK   64
#define NS     16
#define NP     8
#define RB     8

typedef float f32x2 __attribute__((ext_vector_type(2)));
typedef float f32x4 __attribute__((ext_vector_type(4)));
typedef short bf16x8 __attribute__((ext_vector_type(8)));
typedef short bf16x8u __attribute__((ext_vector_type(8), aligned(4)));
typedef unsigned int u32x4 __attribute__((ext_vector_type(4)));

// ws layout (bytes)
#define WS_PA  0
#define WS_PW  (256 * 1024)
#define WS_PE  (512 * 1024)
#define WS_KR  (1ull * 1024 * 1024)    // ushort[1024][2][528]  = 2.1 MB
#define WS_ZL  (4ull * 1024 * 1024)    // f32 [16][8][1024][64] = 32 MB
#define WS_ZT  (36ull * 1024 * 1024)   // ushort[1024][128][64] = 16 MB
#define WS_W2  (52ull * 1024 * 1024)   // ushort[1024][256][64] = 32 MB
#define WS_UBF (84ull * 1024 * 1024)   // ushort[8][16][1024][256] = 64 MB
#define WS_NEED (148ull * 1024 * 1024)

__device__ __forceinline__ unsigned int f2bf(float x) {
    unsigned int u = __builtin_bit_cast(unsigned int, x);
    u = (u + 0x7FFFu + ((u >> 16) & 1u)) >> 16;
    return u & 0xFFFFu;
}

__device__ __forceinline__ void gload_lds16(const void* g, void* l) {
    __builtin_amdgcn_global_load_lds((const __attribute__((address_space(1))) void*)g,
                                     (__attribute__((address_space(3))) void*)l,
                                     16, 0, 0);
}

__device__ __forceinline__ float quad_reduce_add(float y) {
    int t = __builtin_amdgcn_mov_dpp(__builtin_bit_cast(int, y), 0xB1, 0xF, 0xF, true);
    y += __builtin_bit_cast(float, t);
    t = __builtin_amdgcn_mov_dpp(__builtin_bit_cast(int, y), 0x4E, 0xF, 0xF, true);
    y += __builtin_bit_cast(float, t);
    return y;
}

// ---------------------------------------------------------------- K0: params
__global__ void k0_params(const float* __restrict__ A, const float* __restrict__ Bm,
                          const float* __restrict__ C, const float* __restrict__ dt,
                          float* __restrict__ pa, float* __restrict__ pw,
                          float* __restrict__ pE) {
    int i = blockIdx.x * 256 + threadIdx.x;
    if (i >= HID * STATE) return;
    int n = i & (STATE - 1);
    float aexp = expf(A[i]);
    float dtn  = dt[n];
    float a    = expf(-aexp * dtn);
    pa[i] = a;
    pw[i] = C[i] * (Bm[i] * (1.0f - a) / aexp);
    pE[i] = expf(-aexp * dtn * (float)TC);
}

// ------------------------------------------- kKR: reversed conv-kernel tables
__global__ void k_kr(const float* __restrict__ pa, const float* __restrict__ pw,
                     const float* __restrict__ Dv, unsigned short* __restrict__ KR2) {
    __shared__ float K[256];
    int d = blockIdx.x, n = threadIdx.x;
    float a = pa[d * 64 + n];
    float v = pw[d * 64 + n];
    float dvd = Dv[d];
    for (int t = 0; t < 256; t++) {
        float s = v;
        #pragma unroll
        for (int off = 1; off < 64; off <<= 1) s += __shfl_xor(s, off);
        if (n == 0) K[t] = s + (t == 0 ? dvd : 0.0f);
        v *= a;
    }
    __syncthreads();
    unsigned short* kd = KR2 + (size_t)d * 1056;
    for (int i = n; i < 528; i += 64) {
        int x0 = 255 - i;
        int x1 = 254 - i;
        kd[i]       = (x0 >= 0) ? (unsigned short)f2bf(K[x0]) : 0;
        kd[528 + i] = (x1 >= 0) ? (unsigned short)f2bf(K[x1]) : 0;
    }
}

// ------------------------------------------- kW2: W2[d][t][n] = w_n * a_n^{t+1}
__global__ void k_w2(const float* __restrict__ pa, const float* __restrict__ pw,
                     unsigned short* __restrict__ W2) {
    int d = blockIdx.x, n = threadIdx.x;
    float a = pa[d * 64 + n];
    float v = pw[d * 64 + n] * a;
    unsigned short* wd = W2 + (size_t)d * 256 * 64 + n;
    for (int t = 0; t < 256; t++) { wd[(size_t)t * 64] = (unsigned short)f2bf(v); v *= a; }
}

// ------------------------------------------- K1: chunk-local end states + ubfT
// All-wave transpose: wave w converts t-rows [w*8, w*8+8) of each tile.
__global__ __launch_bounds__(256, 3) void k1_locals(const float* __restrict__ u,
                                                    const float* __restrict__ pa,
                                                    float* __restrict__ zl,
                                                    unsigned short* __restrict__ ubf) {
    __shared__ float utile[2][TT * DBLK];
    int bid  = blockIdx.x;
    int dset = bid & 15;
    int b    = (bid >> 4) & 7;
    int c    = bid >> 7;                    // 0..15
    int w    = threadIdx.x >> 6;
    int lane = threadIdx.x & 63;
    int dl   = lane >> 2, p = lane & 3;
    int d    = dset * DBLK + w * 16 + dl;

    f32x2 a2[NP], z2[NP];
    {
        const f32x2* pap = (const f32x2*)(pa + (size_t)d * STATE + p * NS);
        #pragma unroll
        for (int j = 0; j < NP; j++) a2[j] = pap[j];
    }
    #pragma unroll
    for (int j = 0; j < NP; j++) { z2[j].x = 0.f; z2[j].y = 0.f; }

    const char* ubase = (const char*)(u + ((size_t)b * SEQLEN + (size_t)c * TC) * HID
                                        + (size_t)dset * DBLK);

    #define ISSUE_TILE(t, buf)                                                        \
        {                                                                             \
            _Pragma("unroll")                                                         \
            for (int k = 0; k < 2; k++) {                                             \
                int off = w * 2048 + k * 1024 + lane * 16;                            \
                int row = off >> 8;                                                   \
                int col = off & 255;                                                  \
                const float* src = (const float*)(ubase + ((size_t)((t) * TT + row)) * (HID * 4) + col); \
                float* dst = &utile[buf][w * 512 + k * 256];                           \
                gload_lds16(src, dst);                                                \
            }                                                                         \
        }

    ISSUE_TILE(0, 0);
    __syncthreads();
    int cur = 0;
    for (int tile = 0; tile < NTILE; ++tile) {
        if (tile + 1 < NTILE) ISSUE_TILE(tile + 1, cur ^ 1);
        const float* ut = &utile[cur][w * 16 + dl];
        #pragma unroll
        for (int r = 0; r < TT; r++) {
            float uss = ut[r * DBLK];
            f32x2 us; us.x = uss; us.y = uss;
            #pragma unroll
            for (int j = 0; j < NP; j++)
                z2[j] = __builtin_elementwise_fma(a2[j], z2[j], us);
        }
        // all-wave transpose: wave w handles t-rows [w*8, w*8+8) -> bf16 [d][t]
        if (ubf != nullptr) {
            const float* colp = &utile[cur][lane];     // column d = dset*64+lane
            unsigned int pk[4];
            #pragma unroll
            for (int q = 0; q < 4; q++) {
                unsigned int lo = f2bf(colp[(w * 8 + 2 * q) * DBLK]);
                unsigned int hi = f2bf(colp[(w * 8 + 2 * q + 1) * DBLK]);
                pk[q] = lo | (hi << 16);
            }
            size_t drow = (size_t)(b * 16 + c) * 1024 + dset * 64 + lane;
            unsigned int* dst = (unsigned int*)((char*)ubf + drow * 512
                                                + (size_t)tile * 64 + w * 16);
            *(u32x4*)dst = (u32x4){pk[0], pk[1], pk[2], pk[3]};
        }
        __syncthreads();
        cur ^= 1;
    }

    f32x2* zp = (f32x2*)(zl + (((size_t)c * BATCH + b) * HID + d) * STATE + p * NS);
    #pragma unroll
    for (int j = 0; j < NP; j++) zp[j] = z2[j];
}

// ---------------------------------- K2: prefix scan over chunks
__global__ void k2_scan(const float* __restrict__ pE, float* __restrict__ zl) {
    int i  = blockIdx.x * 256 + threadIdx.x;
    int dn = i & (HID * STATE - 1);
    float E = pE[dn];
    size_t stride = (size_t)BATCH * HID * STATE;
    float g = zl[i];
    for (int c = 1; c < NC - 1; c++) {
        float v = zl[i + c * stride];
        g = fmaf(E, g, v);
        zl[i + c * stride] = g;
    }
}

// ---------------------------------- kZT: ZT[d][bc][n] bf16 chunk-init states
__global__ void k_zt(const float* __restrict__ zl, unsigned short* __restrict__ ZT) {
    int idx = blockIdx.x * 256 + threadIdx.x;
    int n  = idx & 63;
    int bc = (idx >> 6) & 127;
    int d  = idx >> 13;
    int b = bc >> 4, c = bc & 15;
    float z = 0.0f;
    if (c > 0)
        z = zl[((size_t)((c - 1) * 8 + b) * 1024 + d) * 64 + n];
    ZT[idx] = (unsigned short)f2bf(z);
}

// ---------------------------------- K3 MFMA: whole-tile staged, barrier-free core
// block: (dg 16-d, bcg 16-bc), FULL 256 t. 512 thr = 8 waves; wave owns 2 d.
// u-tile (16d x 16bc x 256s bf16 = 128KB) staged ONCE via global_load_lds with
// chunk-XOR swizzle cs' = cs ^ (bc&7); one barrier; then pure MFMA + L1 KR reads.
__global__ __launch_bounds__(512, 2) void k3_mfma(const unsigned short* __restrict__ ubf,
                                                  const unsigned short* __restrict__ KR2,
                                                  const unsigned short* __restrict__ W2,
                                                  const unsigned short* __restrict__ ZT,
                                                  float* __restrict__ out) {
    __shared__ __align__(16) char smem[16 * 16 * 512];   // 128 KB
    int bid = blockIdx.x;
    int bcg = bid & 7;
    int dg  = bid >> 3;                 // 0..63
    int tid = threadIdx.x;
    int w   = tid >> 6;                 // wave 0..7
    int l   = tid & 63;
    int g   = l >> 4;                   // 0..3
    int r16 = l & 15;

    // ---- stage the whole u-tile: 16 issues/thread, 1KB per wave-issue
    {
        int lsub = l >> 5;              // 0/1: which bc of the issue's pair
        int cs_p = l & 31;              // swizzled chunk slot
        #pragma unroll
        for (int i = 0; i < 16; i++) {
            int dloc = w * 2 + (i >> 3);
            int bc   = (i & 7) * 2 + lsub;
            int cs   = cs_p ^ (bc & 7);             // global chunk index
            int gbc  = bcg * 16 + bc;
            const unsigned short* src = ubf + ((size_t)gbc * 1024 + dg * 16 + dloc) * 256
                                            + cs * 8;
            char* dst = &smem[((dloc * 16 + (i & 7) * 2) * 512)];
            gload_lds16(src, dst);
        }
    }
    __syncthreads();

    f32x4 acc[2][16];
    #pragma unroll
    for (int dd = 0; dd < 2; dd++)
        #pragma unroll
        for (int tt = 0; tt < 16; tt++) acc[dd][tt] = (f32x4){0.f, 0.f, 0.f, 0.f};

    const unsigned short* krd0 = KR2 + (size_t)(dg * 16 + w * 2) * 1056;
    int L0 = 255 + 8 * g - r16;

    // ---- barrier-free conv core: 8 slabs x (2 dd x up-to-16 tt) MFMA
    #pragma unroll
    for (int sk = 0; sk < 8; sk++) {
        #pragma unroll
        for (int dd = 0; dd < 2; dd++) {
            int dloc = w * 2 + dd;
            int lds_off = (dloc * 16 + r16) * 512 + (((sk * 4 + g) ^ (r16 & 7)) * 16);
            bf16x8 B = *(const bf16x8*)(&smem[lds_off]);
            const unsigned short* krd = krd0 + dd * 1056;
            #pragma unroll
            for (int tt = 0; tt < 16; tt++) {
                if (tt * 16 + 15 >= sk * 32) {       // triangular skip (uniform)
                    int i0 = L0 + sk * 32 - tt * 16;
                    bf16x8 A = (bf16x8)*(const bf16x8u*)(krd + (i0 & 1) * 528 + (i0 & ~1));
                    acc[dd][tt] = __builtin_amdgcn_mfma_f32_16x16x32_bf16(A, B, acc[dd][tt], 0, 0, 0);
                }
            }
        }
    }

    // ---- state-init correction: acc += W2[t][n] x ZT[bc][n]
    #pragma unroll
    for (int dd = 0; dd < 2; dd++) {
        int d = dg * 16 + w * 2 + dd;
        const unsigned short* ztd = ZT + ((size_t)d * 128 + bcg * 16) * 64;
        const unsigned short* w2d = W2 + (size_t)d * 256 * 64;
        #pragma unroll
        for (int ns = 0; ns < 2; ns++) {
            bf16x8 Bz = (bf16x8)*(const bf16x8u*)(ztd + (size_t)r16 * 64 + ns * 32 + 8 * g);
            #pragma unroll
            for (int tt = 0; tt < 16; tt++) {
                bf16x8 Aw = (bf16x8)*(const bf16x8u*)(w2d + (size_t)(tt * 16 + r16) * 64 + ns * 32 + 8 * g);
                acc[dd][tt] = __builtin_amdgcn_mfma_f32_16x16x32_bf16(Aw, Bz, acc[dd][tt], 0, 0, 0);
            }
        }
    }

    // ---- epilogue: LDS transpose (padded strides) -> full 64B-line stores
    float* eps = (float*)&smem[0];
    int rid = tid >> 1, half = tid & 1;
    int trow_r = rid >> 4, bc_r = rid & 15;
    int gbc_r = bcg * 16 + bc_r;
    int bo = gbc_r >> 4, co = gbc_r & 15;
    float* pbase = out + ((size_t)bo * SEQLEN + (size_t)co * TC + trow_r) * HID
                       + dg * 16 + half * 8;
    #pragma unroll
    for (int tt = 0; tt < 16; tt++) {
        __syncthreads();
        #pragma unroll
        for (int dd = 0; dd < 2; dd++) {
            #pragma unroll
            for (int rr = 0; rr < 4; rr++)
                eps[(g * 4 + rr) * 278 + r16 * 17 + (w * 2 + dd)] = acc[dd][tt][rr];
        }
        __syncthreads();
        f32x4 v0, v1;
        #pragma unroll
        for (int j = 0; j < 4; j++) v0[j] = eps[trow_r * 278 + bc_r * 17 + half * 8 + j];
        #pragma unroll
        for (int j = 0; j < 4; j++) v1[j] = eps[trow_r * 278 + bc_r * 17 + half * 8 + 4 + j];
        *(f32x4*)(pbase + (size_t)tt * 16 * HID)     = v0;
        *(f32x4*)(pbase + (size_t)tt * 16 * HID + 4) = v1;
    }
}

// ---------------------------------- fallback scalar K3 (round-10 best)
__global__ __launch_bounds__(256, 3) void k3_scalar(const float* __restrict__ u,
                                                    const float* __restrict__ Dv,
                                                    const float* __restrict__ pa,
                                                    const float* __restrict__ pw,
                                                    const float* __restrict__ zl,
                                                    float* __restrict__ out) {
    __shared__ float utile[2][TT * DBLK];
    int bid  = blockIdx.x;
    int dset = bid & 15;
    int b    = (bid >> 4) & 7;
    int c    = bid >> 7;
    int w    = threadIdx.x >> 6;
    int lane = threadIdx.x & 63;
    int dl   = lane >> 2, p = lane & 3;
    int d    = dset * DBLK + w * 16 + dl;

    f32x2 a2[NP], w2[NP], z2[NP];
    {
        const f32x2* pap = (const f32x2*)(pa + (size_t)d * STATE + p * NS);
        const f32x2* pwp = (const f32x2*)(pw + (size_t)d * STATE + p * NS);
        #pragma unroll
        for (int j = 0; j < NP; j++) { a2[j] = pap[j]; w2[j] = pwp[j]; }
    }
    if (c == 0) {
        #pragma unroll
        for (int j = 0; j < NP; j++) { z2[j].x = 0.f; z2[j].y = 0.f; }
    } else {
        size_t stride = (size_t)BATCH * HID * STATE;
        const f32x2* zp = (const f32x2*)(zl + (size_t)(c - 1) * stride +
                                         ((size_t)b * HID + d) * STATE + p * NS);
        #pragma unroll
        for (int j = 0; j < NP; j++) z2[j] = zp[j];
    }

    float dvd = Dv[d];
    const char* ubase = (const char*)(u + ((size_t)b * SEQLEN + (size_t)c * TC) * HID
                                        + (size_t)dset * DBLK);
    float* po = out + ((size_t)b * SEQLEN + (size_t)c * TC) * HID + d;

    ISSUE_TILE(0, 0);
    __syncthreads();
    int cur = 0;
    for (int tile = 0; tile < NTILE; ++tile) {
        if (tile + 1 < NTILE) ISSUE_TILE(tile + 1, cur ^ 1);
        const float* ut = &utile[cur][w * 16 + dl];
        float* po_t = po + (size_t)tile * TT * HID;
        #pragma unroll
        for (int r0 = 0; r0 < TT; r0 += RB) {
            float ylane[RB], usv[RB];
            #pragma unroll
            for (int i = 0; i < RB; i++) {
                float uss = ut[(r0 + i) * DBLK];
                usv[i] = uss;
                f32x2 us; us.x = uss; us.y = uss;
                #pragma unroll
                for (int j = 0; j < NP; j++)
                    z2[j] = __builtin_elementwise_fma(a2[j], z2[j], us);
                f32x2 acc0 = z2[0] * w2[0];
                f32x2 acc1 = z2[1] * w2[1];
                #pragma unroll
                for (int j = 2; j < NP; j += 2) {
                    acc0 = __builtin_elementwise_fma(z2[j + 0], w2[j + 0], acc0);
                    acc1 = __builtin_elementwise_fma(z2[j + 1], w2[j + 1], acc1);
                }
                acc0 += acc1;
                ylane[i] = acc0.x + acc0.y;
            }
            #pragma unroll
            for (int i = 0; i < RB; i++) ylane[i] = quad_reduce_add(ylane[i]);
            #pragma unroll
            for (int i = 0; i < RB; i++)
                po_t[(size_t)(r0 + i) * HID] = fmaf(dvd, usv[i], ylane[i]);
        }
        __syncthreads();
        cur ^= 1;
    }
}

extern "C" void kernel_launch(void* const* d_in, const int* in_sizes, int n_in,
                              void* d_out, int out_size, void* d_ws, size_t ws_size,
                              hipStream_t stream) {
    const float* u  = (const float*)d_in[0];
    const float* A  = (const float*)d_in[1];
    const float* Bm = (const float*)d_in[2];
    const float* C  = (const float*)d_in[3];
    const float* Dv = (const float*)d_in[4];
    const float* dt = (const float*)d_in[5];
    float* out = (float*)d_out;

    char* ws = (char*)d_ws;
    float* pa = (float*)(ws + WS_PA);
    float* pw = (float*)(ws + WS_PW);
    float* pE = (float*)(ws + WS_PE);
    unsigned short* KR2 = (unsigned short*)(ws + WS_KR);
    float* zl = (float*)(ws + WS_ZL);
    unsigned short* ZT  = (unsigned short*)(ws + WS_ZT);
    unsigned short* W2  = (unsigned short*)(ws + WS_W2);
    unsigned short* UBF = (unsigned short*)(ws + WS_UBF);

    bool mfma = (ws_size >= WS_NEED);

    k0_params<<<(HID * STATE) / 256, 256, 0, stream>>>(A, Bm, C, dt, pa, pw, pE);
    k1_locals<<<16 * 8 * NC, 256, 0, stream>>>(u, pa, zl, mfma ? UBF : nullptr);
    k2_scan<<<(BATCH * HID * STATE) / 256, 256, 0, stream>>>(pE, zl);

    if (mfma) {
        k_kr<<<1024, 64, 0, stream>>>(pa, pw, Dv, KR2);
        k_w2<<<1024, 64, 0, stream>>>(pa, pw, W2);
        k_zt<<<(1024 * 128 * 64) / 256, 256, 0, stream>>>(zl, ZT);
        k3_mfma<<<64 * 8, 512, 0, stream>>>(UBF, KR2, W2, ZT, out);
    } else {
        k3_scalar<<<16 * 8 * NC, 256, 0, stream>>>(u, Dv, pa, pw, zl, out);
    }
}

// Round 14
// 180.224 us; speedup vs baseline: 1.5838x; 1.5838x over previous
//
#include <hip/hip_runtime.h>
#include <math.h>

#define BATCH  8
#define SEQLEN 4096
#define HID    1024
#define STATE  64
#define NC     16
#define TC     (SEQLEN / NC)   // 256 steps per chunk
#define TT     32              // time rows per LDS tile (k1/scalar path)
#define NTILE  (TC / TT)
#define DBLK   64
#define NS     16
#define NP     8
#define RB     8

typedef float f32x2 __attribute__((ext_vector_type(2)));
typedef float f32x4 __attribute__((ext_vector_type(4)));
typedef short bf16x8 __attribute__((ext_vector_type(8)));
typedef unsigned int u32x4 __attribute__((ext_vector_type(4)));

// ws layout (bytes)
#define WS_PA   0
#define WS_PW   (256 * 1024)
#define WS_PE   (512 * 1024)
#define WS_PL2  (768 * 1024)
#define WS_ZL   (1ull  * 1024 * 1024)   // f32 [15][8][1024][64] = 30 MB
#define WS_ZT   (36ull * 1024 * 1024)   // ushort[1024][128][64] = 16 MB
#define WS_W2F  (56ull * 1024 * 1024)   // ushort[1024][16384]   = 32 MB (fragment-major)
#define WS_KRF  (92ull * 1024 * 1024)   // ushort[1024][8192]    = 16 MB (fragment-major)
#define WS_NEED (148ull * 1024 * 1024)

__device__ __forceinline__ unsigned int f2bf(float x) {
    unsigned int u = __builtin_bit_cast(unsigned int, x);
    u = (u + 0x7FFFu + ((u >> 16) & 1u)) >> 16;
    return u & 0xFFFFu;
}

__device__ __forceinline__ void gload_lds16(const void* g, void* l) {
    __builtin_amdgcn_global_load_lds((const __attribute__((address_space(1))) void*)g,
                                     (__attribute__((address_space(3))) void*)l,
                                     16, 0, 0);
}

__device__ __forceinline__ float quad_reduce_add(float y) {
    int t = __builtin_amdgcn_mov_dpp(__builtin_bit_cast(int, y), 0xB1, 0xF, 0xF, true);
    y += __builtin_bit_cast(float, t);
    t = __builtin_amdgcn_mov_dpp(__builtin_bit_cast(int, y), 0x4E, 0xF, 0xF, true);
    y += __builtin_bit_cast(float, t);
    return y;
}

// ---------------------------------------------------------------- K0: params
__global__ void k0_params(const float* __restrict__ A, const float* __restrict__ Bm,
                          const float* __restrict__ C, const float* __restrict__ dt,
                          float* __restrict__ pa, float* __restrict__ pw,
                          float* __restrict__ pE, float* __restrict__ pl2) {
    int i = blockIdx.x * 256 + threadIdx.x;
    if (i >= HID * STATE) return;
    int n = i & (STATE - 1);
    float aexp = expf(A[i]);
    float dtn  = dt[n];
    float a    = expf(-aexp * dtn);
    pa[i]  = a;
    pw[i]  = C[i] * (Bm[i] * (1.0f - a) / aexp);
    pE[i]  = expf(-aexp * dtn * (float)TC);
    pl2[i] = -aexp * dtn * 1.44269504088896340736f;   // log2(a)
}

// ------------------------------------------- K1: chunk-local end states (r10-proven)
__global__ __launch_bounds__(256, 3) void k1_locals(const float* __restrict__ u,
                                                    const float* __restrict__ pa,
                                                    float* __restrict__ zl) {
    __shared__ float utile[2][TT * DBLK];
    int bid  = blockIdx.x;
    int dset = bid & 15;
    int b    = (bid >> 4) & 7;
    int c    = bid >> 7;                       // chunk 0..NC-2
    int w    = threadIdx.x >> 6;
    int lane = threadIdx.x & 63;
    int dl   = lane >> 2, p = lane & 3;
    int d    = dset * DBLK + w * 16 + dl;

    f32x2 a2[NP], z2[NP];
    {
        const f32x2* pap = (const f32x2*)(pa + (size_t)d * STATE + p * NS);
        #pragma unroll
        for (int j = 0; j < NP; j++) a2[j] = pap[j];
    }
    #pragma unroll
    for (int j = 0; j < NP; j++) { z2[j].x = 0.f; z2[j].y = 0.f; }

    const char* ubase = (const char*)(u + ((size_t)b * SEQLEN + (size_t)c * TC) * HID
                                        + (size_t)dset * DBLK);

    #define ISSUE_TILE(t, buf)                                                        \
        {                                                                             \
            _Pragma("unroll")                                                         \
            for (int k = 0; k < 2; k++) {                                             \
                int off = w * 2048 + k * 1024 + lane * 16;                            \
                int row = off >> 8;                                                   \
                int col = off & 255;                                                  \
                const float* src = (const float*)(ubase + ((size_t)((t) * TT + row)) * (HID * 4) + col); \
                float* dst = &utile[buf][w * 512 + k * 256];                           \
                gload_lds16(src, dst);                                                \
            }                                                                         \
        }

    ISSUE_TILE(0, 0);
    __syncthreads();
    int cur = 0;
    for (int tile = 0; tile < NTILE; ++tile) {
        if (tile + 1 < NTILE) ISSUE_TILE(tile + 1, cur ^ 1);
        const float* ut = &utile[cur][w * 16 + dl];
        #pragma unroll
        for (int r = 0; r < TT; r++) {
            float uss = ut[r * DBLK];
            f32x2 us; us.x = uss; us.y = uss;
            #pragma unroll
            for (int j = 0; j < NP; j++)
                z2[j] = __builtin_elementwise_fma(a2[j], z2[j], us);
        }
        __syncthreads();
        cur ^= 1;
    }

    f32x2* zp = (f32x2*)(zl + (((size_t)c * BATCH + b) * HID + d) * STATE + p * NS);
    #pragma unroll
    for (int j = 0; j < NP; j++) zp[j] = z2[j];
}

// ---------------------------------- K2 (fallback): prefix scan in-place in zl
__global__ void k2_scan(const float* __restrict__ pE, float* __restrict__ zl) {
    int i  = blockIdx.x * 256 + threadIdx.x;
    int dn = i & (HID * STATE - 1);
    float E = pE[dn];
    size_t stride = (size_t)BATCH * HID * STATE;
    float g = zl[i];
    for (int c = 1; c < NC - 1; c++) {
        float v = zl[i + c * stride];
        g = fmaf(E, g, v);
        zl[i + c * stride] = g;
    }
}

// ---------------------------------- K2-ZT (mfma): scan + emit bf16 chunk-inits
__global__ void k2_zt(const float* __restrict__ pE, const float* __restrict__ zl,
                      unsigned short* __restrict__ ZT) {
    int i = blockIdx.x * 256 + threadIdx.x;     // b*65536 + d*64 + n
    int n = i & 63;
    int d = (i >> 6) & 1023;
    int b = i >> 16;
    float E = pE[d * 64 + n];
    size_t stride = (size_t)BATCH * HID * STATE;
    unsigned short* zt = ZT + (size_t)d * 8192 + (size_t)b * 1024 + n;
    zt[0] = 0;                                   // c=0 init state = 0
    float g = zl[i];                             // end of chunk 0
    zt[64] = (unsigned short)f2bf(g);            // c=1 init
    for (int c = 2; c < 16; c++) {
        g = fmaf(E, g, zl[i + (size_t)(c - 1) * stride]);
        zt[(size_t)c * 64] = (unsigned short)f2bf(g);
    }
}

// ---------------------------------- kKRF: fragment-major conv-kernel table
// KRF[d][m][lane l][j] = K_d[x], x = r16 - 8g + 16m - j (0 if x<0); K(0) += Dv.
__global__ void k_krf(const float* __restrict__ pw, const float* __restrict__ pl2,
                      const float* __restrict__ Dv, unsigned short* __restrict__ KRF) {
    __shared__ float wv[64], e2[64], K[256];
    int d = blockIdx.x, t = threadIdx.x;         // 256 threads
    if (t < 64) { wv[t] = pw[d * 64 + t]; e2[t] = pl2[d * 64 + t]; }
    __syncthreads();
    float s = 0.0f;
    for (int n = 0; n < 64; n++) s += wv[n] * exp2f((float)t * e2[n]);
    if (t == 0) s += Dv[d];
    K[t] = s;
    __syncthreads();
    for (int idx = t; idx < 8192; idx += 256) {
        int j  = idx & 7;
        int ll = (idx >> 3) & 63;
        int m  = idx >> 9;
        int x  = (ll & 15) - 8 * (ll >> 4) + 16 * m - j;
        unsigned short v = 0;
        if (x >= 0) v = (unsigned short)f2bf(K[x]);
        KRF[(size_t)d * 8192 + idx] = v;
    }
}

// ---------------------------------- kW2F: fragment-major state-correction table
// W2F[d][tt][ns][l][j] = w_n * a_n^{t+1}, n = ns*32+8g+j, t = tt*16+r16.
__global__ void k_w2f(const float* __restrict__ pw, const float* __restrict__ pl2,
                      unsigned short* __restrict__ W2F) {
    __shared__ float wv[64], e2[64];
    int d = blockIdx.x, t = threadIdx.x;
    if (t < 64) { wv[t] = pw[d * 64 + t]; e2[t] = pl2[d * 64 + t]; }
    __syncthreads();
    for (int idx = t; idx < 16384; idx += 256) {
        int j  = idx & 7;
        int ll = (idx >> 3) & 63;
        int ns = (idx >> 9) & 1;
        int tt = idx >> 10;
        int n  = ns * 32 + 8 * (ll >> 4) + j;
        int tg = tt * 16 + (ll & 15);
        float val = wv[n] * exp2f((float)(tg + 1) * e2[n]);
        W2F[(size_t)d * 16384 + idx] = (unsigned short)f2bf(val);
    }
}

// ---------------------------------- K3 MFMA: 1 wave = 1 d, 16 acc tiles, no spill
__global__ __launch_bounds__(1024, 1) void k3_mfma(const float* __restrict__ u,
                                                   const unsigned short* __restrict__ KRF,
                                                   const unsigned short* __restrict__ W2F,
                                                   const unsigned short* __restrict__ ZT,
                                                   float* __restrict__ out) {
    __shared__ __align__(16) char smem[131072];   // [dl16][bc16][32 slots x 16B], swizzled
    int bid = blockIdx.x;
    int dg  = bid & 63;          // xcd = bid%8 = dg%8 -> same-dg blocks share one L2
    int bcg = bid >> 6;          // 0..7
    int tid = threadIdx.x;
    int w   = tid >> 6;          // wave 0..15, owns d = dg*16 + w
    int l   = tid & 63;
    int g   = l >> 4, r16 = l & 15;
    int d   = dg * 16 + w;

    // ---- phase 1: stage u (f32) -> bf16 LDS, reg-staged, swizzled slots
    {
        int dl = tid & 15;
        int v  = (tid >> 4) & 63;
        int bc = v & 15;
        int sq = v >> 4;
        int gbc = bcg * 16 + bc;
        int bs = gbc >> 4, cs = gbc & 15;
        const float* up = u + ((size_t)(bs * SEQLEN + cs * TC + sq * 64)) * HID
                            + dg * 16 + dl;
        unsigned int rowb = (unsigned int)(dl * 16 + bc) * 512;
        #pragma unroll
        for (int kk = 0; kk < 8; kk++) {
            float uv[8];
            #pragma unroll
            for (int j = 0; j < 8; j++) uv[j] = up[(size_t)(kk * 8 + j) * HID];
            unsigned int pk[4];
            #pragma unroll
            for (int q = 0; q < 4; q++)
                pk[q] = f2bf(uv[2 * q]) | (f2bf(uv[2 * q + 1]) << 16);
            int sc   = sq * 8 + kk;
            int slot = (sc + 4 * (bc & 7) + 5 * dl) & 31;
            *(u32x4*)(&smem[rowb + slot * 16]) = (u32x4){pk[0], pk[1], pk[2], pk[3]};
        }
    }
    __syncthreads();

    f32x4 acc[16];
    #pragma unroll
    for (int tt = 0; tt < 16; tt++) acc[tt] = (f32x4){0.f, 0.f, 0.f, 0.f};

    const unsigned short* krf = KRF + (size_t)d * 8192 + l * 8;
    unsigned int rowr = (unsigned int)(w * 16 + r16) * 512;
    int rot = (4 * (r16 & 7) + 5 * w) & 31;

    // ---- conv core, half 1: m = 0..7 (A-frags batched, all indices static)
    {
        bf16x8 Af[8];
        #pragma unroll
        for (int mm = 0; mm < 8; mm++)
            Af[mm] = *(const bf16x8*)(krf + (size_t)mm * 512);
        #pragma unroll
        for (int mm = 0; mm < 8; mm++) {
            #pragma unroll
            for (int sk = 0; sk < 8; sk++) {
                if (2 * sk + mm <= 15) {
                    int slot = ((sk * 4 + g) + rot) & 31;
                    bf16x8 B = *(const bf16x8*)(&smem[rowr + slot * 16]);
                    acc[2 * sk + mm] =
                        __builtin_amdgcn_mfma_f32_16x16x32_bf16(Af[mm], B, acc[2 * sk + mm], 0, 0, 0);
                }
            }
        }
    }
    __builtin_amdgcn_sched_barrier(0);
    // ---- conv core, half 2: m = 8..15
    {
        bf16x8 Af[8];
        #pragma unroll
        for (int mm = 0; mm < 8; mm++)
            Af[mm] = *(const bf16x8*)(krf + (size_t)(8 + mm) * 512);
        #pragma unroll
        for (int mm = 0; mm < 8; mm++) {
            #pragma unroll
            for (int sk = 0; sk < 4; sk++) {
                if (2 * sk + 8 + mm <= 15) {
                    int slot = ((sk * 4 + g) + rot) & 31;
                    bf16x8 B = *(const bf16x8*)(&smem[rowr + slot * 16]);
                    acc[2 * sk + 8 + mm] =
                        __builtin_amdgcn_mfma_f32_16x16x32_bf16(Af[mm], B, acc[2 * sk + 8 + mm], 0, 0, 0);
                }
            }
        }
    }
    __builtin_amdgcn_sched_barrier(0);

    // ---- state-init correction: acc[tt] += W2F(tt,ns) x ZT(bc,n), 4 groups of 4 tt
    {
        const unsigned short* ztd = ZT + (size_t)d * 8192 + (size_t)bcg * 1024;
        bf16x8 Bz0 = *(const bf16x8*)(ztd + (size_t)r16 * 64 + 0 * 32 + 8 * g);
        bf16x8 Bz1 = *(const bf16x8*)(ztd + (size_t)r16 * 64 + 1 * 32 + 8 * g);
        const unsigned short* w2f = W2F + (size_t)d * 16384 + l * 8;
        #pragma unroll
        for (int grp = 0; grp < 4; grp++) {
            bf16x8 Aw[8];
            #pragma unroll
            for (int q = 0; q < 8; q++) {
                int tt = grp * 4 + (q >> 1);
                int ns = q & 1;
                Aw[q] = *(const bf16x8*)(w2f + (size_t)(tt * 2 + ns) * 512);
            }
            #pragma unroll
            for (int q = 0; q < 8; q++) {
                int tt = grp * 4 + (q >> 1);
                acc[grp * 4 + (q >> 1)] =
                    __builtin_amdgcn_mfma_f32_16x16x32_bf16(Aw[q], (q & 1) ? Bz1 : Bz0,
                                                            acc[tt], 0, 0, 0);
            }
            __builtin_amdgcn_sched_barrier(0);
        }
    }

    // ---- epilogue: padded LDS transpose -> full 64B-line stores
    float* eps = (float*)smem;
    int p = tid >> 2, sub = tid & 3;
    int t16r = p >> 4, bcr = p & 15;
    int gbcr = bcg * 16 + bcr;
    int bo = gbcr >> 4, co = gbcr & 15;
    float* pout = out + ((size_t)(bo * SEQLEN + co * TC + t16r)) * HID + dg * 16 + sub * 4;
    #pragma unroll
    for (int tt = 0; tt < 16; tt++) {
        __syncthreads();
        #pragma unroll
        for (int rr = 0; rr < 4; rr++)
            eps[((g * 4 + rr) * 16 + r16) * 21 + w] = acc[tt][rr];
        __syncthreads();
        f32x4 vv;
        #pragma unroll
        for (int j = 0; j < 4; j++) vv[j] = eps[p * 21 + sub * 4 + j];
        *(f32x4*)(pout + (size_t)(tt * 16) * HID) = vv;
    }
}

// ---------------------------------- fallback scalar K3 (round-10 best, 118 us)
__global__ __launch_bounds__(256, 3) void k3_scalar(const float* __restrict__ u,
                                                    const float* __restrict__ Dv,
                                                    const float* __restrict__ pa,
                                                    const float* __restrict__ pw,
                                                    const float* __restrict__ zl,
                                                    float* __restrict__ out) {
    __shared__ float utile[2][TT * DBLK];
    int bid  = blockIdx.x;
    int dset = bid & 15;
    int b    = (bid >> 4) & 7;
    int c    = bid >> 7;
    int w    = threadIdx.x >> 6;
    int lane = threadIdx.x & 63;
    int dl   = lane >> 2, p = lane & 3;
    int d    = dset * DBLK + w * 16 + dl;

    f32x2 a2[NP], w2[NP], z2[NP];
    {
        const f32x2* pap = (const f32x2*)(pa + (size_t)d * STATE + p * NS);
        const f32x2* pwp = (const f32x2*)(pw + (size_t)d * STATE + p * NS);
        #pragma unroll
        for (int j = 0; j < NP; j++) { a2[j] = pap[j]; w2[j] = pwp[j]; }
    }
    if (c == 0) {
        #pragma unroll
        for (int j = 0; j < NP; j++) { z2[j].x = 0.f; z2[j].y = 0.f; }
    } else {
        size_t stride = (size_t)BATCH * HID * STATE;
        const f32x2* zp = (const f32x2*)(zl + (size_t)(c - 1) * stride +
                                         ((size_t)b * HID + d) * STATE + p * NS);
        #pragma unroll
        for (int j = 0; j < NP; j++) z2[j] = zp[j];
    }

    float dvd = Dv[d];
    const char* ubase = (const char*)(u + ((size_t)b * SEQLEN + (size_t)c * TC) * HID
                                        + (size_t)dset * DBLK);
    float* po = out + ((size_t)b * SEQLEN + (size_t)c * TC) * HID + d;

    ISSUE_TILE(0, 0);
    __syncthreads();
    int cur = 0;
    for (int tile = 0; tile < NTILE; ++tile) {
        if (tile + 1 < NTILE) ISSUE_TILE(tile + 1, cur ^ 1);
        const float* ut = &utile[cur][w * 16 + dl];
        float* po_t = po + (size_t)tile * TT * HID;
        #pragma unroll
        for (int r0 = 0; r0 < TT; r0 += RB) {
            float ylane[RB], usv[RB];
            #pragma unroll
            for (int i = 0; i < RB; i++) {
                float uss = ut[(r0 + i) * DBLK];
                usv[i] = uss;
                f32x2 us; us.x = uss; us.y = uss;
                #pragma unroll
                for (int j = 0; j < NP; j++)
                    z2[j] = __builtin_elementwise_fma(a2[j], z2[j], us);
                f32x2 acc0 = z2[0] * w2[0];
                f32x2 acc1 = z2[1] * w2[1];
                #pragma unroll
                for (int j = 2; j < NP; j += 2) {
                    acc0 = __builtin_elementwise_fma(z2[j + 0], w2[j + 0], acc0);
                    acc1 = __builtin_elementwise_fma(z2[j + 1], w2[j + 1], acc1);
                }
                acc0 += acc1;
                ylane[i] = acc0.x + acc0.y;
            }
            #pragma unroll
            for (int i = 0; i < RB; i++) ylane[i] = quad_reduce_add(ylane[i]);
            #pragma unroll
            for (int i = 0; i < RB; i++)
                po_t[(size_t)(r0 + i) * HID] = fmaf(dvd, usv[i], ylane[i]);
        }
        __syncthreads();
        cur ^= 1;
    }
}

extern "C" void kernel_launch(void* const* d_in, const int* in_sizes, int n_in,
                              void* d_out, int out_size, void* d_ws, size_t ws_size,
                              hipStream_t stream) {
    const float* u  = (const float*)d_in[0];
    const float* A  = (const float*)d_in[1];
    const float* Bm = (const float*)d_in[2];
    const float* C  = (const float*)d_in[3];
    const float* Dv = (const float*)d_in[4];
    const float* dt = (const float*)d_in[5];
    float* out = (float*)d_out;

    char* ws = (char*)d_ws;
    float* pa  = (float*)(ws + WS_PA);
    float* pw  = (float*)(ws + WS_PW);
    float* pE  = (float*)(ws + WS_PE);
    float* pl2 = (float*)(ws + WS_PL2);
    float* zl  = (float*)(ws + WS_ZL);
    unsigned short* ZT  = (unsigned short*)(ws + WS_ZT);
    unsigned short* W2F = (unsigned short*)(ws + WS_W2F);
    unsigned short* KRF = (unsigned short*)(ws + WS_KRF);

    bool mfma = (ws_size >= WS_NEED);

    k0_params<<<(HID * STATE) / 256, 256, 0, stream>>>(A, Bm, C, dt, pa, pw, pE, pl2);
    k1_locals<<<16 * 8 * (NC - 1), 256, 0, stream>>>(u, pa, zl);

    if (mfma) {
        k_krf<<<1024, 256, 0, stream>>>(pw, pl2, Dv, KRF);
        k_w2f<<<1024, 256, 0, stream>>>(pw, pl2, W2F);
        k2_zt<<<(BATCH * HID * STATE) / 256, 256, 0, stream>>>(pE, zl, ZT);
        k3_mfma<<<512, 1024, 0, stream>>>(u, KRF, W2F, ZT, out);
    } else {
        k2_scan<<<(BATCH * HID * STATE) / 256, 256, 0, stream>>>(pE, zl);
        k3_scalar<<<16 * 8 * NC, 256, 0, stream>>>(u, Dv, pa, pw, zl, out);
    }
}